// Round 11
// baseline (662.913 us; speedup 1.0000x reference)
//
#include <hip/hip_runtime.h>

// 3-layer LSTM (145->150->150->32), T=64, B=4096, fp16 MFMA, f32 state.
// Pipeline: prep_w -> gemm0(x->xg0) -> rec0(xg0->h0) -> gemm1(h0->xg1)
//        -> rec1f2(xg1 -> y): layer-1 recurrence + fused xg2 GEMM (Wih2) +
//           layer-2 recurrence running 2 steps behind on waves 8-9, xg2 via LDS.
// R8: lgkm-only barriers everywhere (global stores never drained at barriers).
// R10: rec1f fusion of Wih2 GEMM; slim rec32. R11: rec32 + xg2 global round-trip
//      eliminated -- layer 2 lives in rec1f2's waves 8-9, xg2 through LDS dbuf.

typedef _Float16 f16;
typedef _Float16 f16x8 __attribute__((ext_vector_type(8)));
typedef _Float16 f16x4 __attribute__((ext_vector_type(4)));
typedef float f32x4 __attribute__((ext_vector_type(4)));

#define T_STEPS 64
#define BATCH 4096

__device__ __forceinline__ float fexp(float x) {
  return __builtin_amdgcn_exp2f(x * 1.44269504088896340736f);
}
__device__ __forceinline__ float sigf(float x) {
  return __builtin_amdgcn_rcpf(1.0f + fexp(-x));
}
__device__ __forceinline__ float tanh_f(float x) {
  return 1.0f - 2.0f * __builtin_amdgcn_rcpf(1.0f + fexp(2.0f * x));
}

#define BAR_LGKM() asm volatile("s_waitcnt lgkmcnt(0)\n\ts_barrier" ::: "memory")

// ============================ weight prep ============================
__global__ __launch_bounds__(256) void prep_w(
    const float* __restrict__ wih0, const float* __restrict__ bih0, const float* __restrict__ bhh0,
    const float* __restrict__ wih1, const float* __restrict__ bih1, const float* __restrict__ bhh1,
    f16* __restrict__ wprep0, f16* __restrict__ wprep1,
    float* __restrict__ bias0, float* __restrict__ bias1) {
  int idx = blockIdx.x * 256 + threadIdx.x;
  constexpr int WE = 640 * 168;
  if (idx < WE) {
    int c = idx / 168, k = idx - c * 168;
    int gate = c / 160, cg = c - gate * 160;
    float v = (cg < 150 && k < 145) ? wih0[(size_t)(gate * 150 + cg) * 145 + k] : 0.f;
    wprep0[idx] = (f16)v;
  } else if (idx < 2 * WE) {
    int e = idx - WE;
    int c = e / 168, k = e - c * 168;
    int gate = c / 160, cg = c - gate * 160;
    float v = (cg < 150 && k < 150) ? wih1[(size_t)(gate * 150 + cg) * 150 + k] : 0.f;
    wprep1[e] = (f16)v;
  } else if (idx < 2 * WE + 640) {
    int c = idx - 2 * WE;
    int gate = c / 160, cg = c - gate * 160;
    bias0[c] = (cg < 150) ? (bih0[gate * 150 + cg] + bhh0[gate * 150 + cg]) : 0.f;
  } else if (idx < 2 * WE + 1280) {
    int c = idx - 2 * WE - 640;
    int gate = c / 160, cg = c - gate * 160;
    bias1[c] = (cg < 150) ? (bih1[gate * 150 + cg] + bhh1[gate * 150 + cg]) : 0.f;
  }
}

// ============================ xg GEMM (R8, proven) ============================
template <int IN_DIM, int SRC_F16>
__global__ __launch_bounds__(512, 4) void gemm_xg4(
    const float* __restrict__ xin_f32, const f16* __restrict__ xin_f16,
    const f16* __restrict__ wprep, const float* __restrict__ bias_pre,
    f16* __restrict__ xg) {
  constexpr int ASTR = 168;
  __shared__ __align__(16) f16 A_lds[128 * ASTR];
  __shared__ __align__(16) f16 W_lds[64 * ASTR];
  __shared__ __align__(16) float bias_lds[640];
  const int tid = threadIdx.x;
  const int mtile = blockIdx.x;
  const int g0 = mtile * 128;

  if constexpr (SRC_F16) {
#pragma unroll
    for (int q = 0; q < 6; ++q) {
      int i = q * 512 + tid;
      if (i < 2688)
        *(f16x8*)(&A_lds[i * 8]) = *(const f16x8*)(xin_f16 + (size_t)g0 * ASTR + (size_t)i * 8);
    }
  } else {
#pragma unroll
    for (int q = 0; q < 10; ++q) {
      int idx = q * 512 + tid;
      int r = idx / 40, c4 = (idx - r * 40) * 4;
      f16x4 o;
      if (c4 + 4 <= IN_DIM) {
        f32x4 v;
        __builtin_memcpy(&v, xin_f32 + (size_t)(g0 + r) * IN_DIM + c4, 16);
#pragma unroll
        for (int j = 0; j < 4; ++j) o[j] = (f16)v[j];
      } else {
#pragma unroll
        for (int j = 0; j < 4; ++j)
          o[j] = (c4 + j < IN_DIM) ? (f16)xin_f32[(size_t)(g0 + r) * IN_DIM + c4 + j] : (f16)0.f;
      }
      *(f16x4*)(&A_lds[r * ASTR + c4]) = o;
    }
  }
  if (tid < 160) *(f32x4*)(&bias_lds[tid * 4]) = *(const f32x4*)(bias_pre + tid * 4);
#pragma unroll
  for (int q = 0; q < 3; ++q) {
    int i = q * 512 + tid;
    if (i < 1344) *(f16x8*)(&W_lds[i * 8]) = *(const f16x8*)(wprep + (size_t)i * 8);
  }
  BAR_LGKM();

  const int l = tid & 63, wv = tid >> 6;
  const int p = wv >> 1, cq = wv & 1;
  const int lrow = l & 15, lk8 = (l >> 4) * 8, r0 = (l >> 4) * 4;
  const int arow0 = (2 * p) * 16 + lrow;
  const int wrow0 = (2 * cq) * 16 + lrow;

  f16x8 pv0, pv1, pv2;
  for (int ch = 0; ch < 10; ++ch) {
    if (ch < 9) {
      const f16* wsrc = wprep + (size_t)(ch + 1) * 10752;
      pv0 = *(const f16x8*)(wsrc + (size_t)tid * 8);
      pv1 = *(const f16x8*)(wsrc + (size_t)(tid + 512) * 8);
      if (tid < 320) pv2 = *(const f16x8*)(wsrc + (size_t)(tid + 1024) * 8);
    }
    const int c0 = ch * 64 + (2 * cq) * 16 + lrow;
    const float bs0 = bias_lds[c0], bs1 = bias_lds[c0 + 16];
    f32x4 a00 = {bs0, bs0, bs0, bs0}, a01 = {bs1, bs1, bs1, bs1};
    f32x4 a10 = a00, a11 = a01;
#pragma unroll
    for (int kc = 0; kc < 5; ++kc) {
      f16x8 a0 = *(const f16x8*)(&A_lds[arow0 * ASTR + kc * 32 + lk8]);
      f16x8 a1 = *(const f16x8*)(&A_lds[(arow0 + 16) * ASTR + kc * 32 + lk8]);
      f16x8 b0 = *(const f16x8*)(&W_lds[wrow0 * ASTR + kc * 32 + lk8]);
      f16x8 b1 = *(const f16x8*)(&W_lds[(wrow0 + 16) * ASTR + kc * 32 + lk8]);
      a00 = __builtin_amdgcn_mfma_f32_16x16x32_f16(a0, b0, a00, 0, 0, 0);
      a01 = __builtin_amdgcn_mfma_f32_16x16x32_f16(a0, b1, a01, 0, 0, 0);
      a10 = __builtin_amdgcn_mfma_f32_16x16x32_f16(a1, b0, a10, 0, 0, 0);
      a11 = __builtin_amdgcn_mfma_f32_16x16x32_f16(a1, b1, a11, 0, 0, 0);
    }
    {
      f16x4 o;
      size_t rg0 = (size_t)(mtile * 8 + 2 * p);
#pragma unroll
      for (int j = 0; j < 4; ++j) o[j] = (f16)a00[j];
      *(f16x4*)(xg + (rg0 * 640 + c0) * 16 + r0) = o;
#pragma unroll
      for (int j = 0; j < 4; ++j) o[j] = (f16)a01[j];
      *(f16x4*)(xg + (rg0 * 640 + c0 + 16) * 16 + r0) = o;
#pragma unroll
      for (int j = 0; j < 4; ++j) o[j] = (f16)a10[j];
      *(f16x4*)(xg + ((rg0 + 1) * 640 + c0) * 16 + r0) = o;
#pragma unroll
      for (int j = 0; j < 4; ++j) o[j] = (f16)a11[j];
      *(f16x4*)(xg + ((rg0 + 1) * 640 + c0 + 16) * 16 + r0) = o;
    }
    if (ch < 9) {
      BAR_LGKM();
      *(f16x8*)(&W_lds[tid * 8]) = pv0;
      *(f16x8*)(&W_lds[(tid + 512) * 8]) = pv1;
      if (tid < 320) *(f16x8*)(&W_lds[(tid + 1024) * 8]) = pv2;
      BAR_LGKM();
    }
  }
}

// ============================ recurrent layer 0 (R8, proven; + carried ptrs) ============================
__global__ __launch_bounds__(640, 2) void lstm_rec(
    const f16* __restrict__ xg, const float* __restrict__ whh,
    f16* __restrict__ hout) {
  constexpr int H = 150, HSTR = 168, CPAD = 640;
  constexpr size_t XG_TSTRIDE = (size_t)256 * CPAD * 16;   // f16 per timestep
  constexpr size_t HO_TSTRIDE = (size_t)BATCH * 168;
  __shared__ __align__(16) f16 hbuf[2][16 * HSTR];
  const int tid = threadIdx.x;
  const int l = tid & 63, w = tid >> 6;
  const int lrow = l & 15, lk8 = (l >> 4) * 8, r0 = (l >> 4) * 4;
  const int col = w * 16 + lrow;
  const int bx = blockIdx.x, b0 = bx * 16;

  for (int i = tid; i < 2 * 16 * HSTR / 8; i += 640) {
    f16x8 z = {};
    *(f16x8*)(&hbuf[0][0] + (size_t)i * 8) = z;
  }

  f16x8 wh[4][5];
#pragma unroll
  for (int g = 0; g < 4; ++g)
#pragma unroll
    for (int kc = 0; kc < 5; ++kc) {
      f16x8 v;
#pragma unroll
      for (int j = 0; j < 8; ++j) {
        int k = kc * 32 + lk8 + j;
        float x = (col < H && k < H) ? whh[((size_t)g * H + col) * H + k] : 0.f;
        v[j] = (f16)x;
      }
      wh[g][kc] = v;
    }
  __syncthreads();

  float creg[4] = {0.f, 0.f, 0.f, 0.f};
  // carried pointers (strength-reduced per-step addressing)
  const f16* xgp = xg + ((size_t)bx * CPAD + col) * 16 + r0;   // + g*160*16 per gate
  f16* houtp = hout + (size_t)b0 * 168 + (size_t)tid * 8;
  f16x4 pv[4];
#pragma unroll
  for (int g = 0; g < 4; ++g) pv[g] = *(const f16x4*)(xgp + (size_t)g * 160 * 16);
  xgp += XG_TSTRIDE;

  for (int t = 0; t < T_STEPS; ++t) {
    const int cur = t & 1, nxt = cur ^ 1;

    f32x4 acc[4];
#pragma unroll
    for (int g = 0; g < 4; ++g) {
#pragma unroll
      for (int j = 0; j < 4; ++j) acc[g][j] = (float)pv[g][j];
    }
    if (t + 1 < T_STEPS) {
#pragma unroll
      for (int g = 0; g < 4; ++g) pv[g] = *(const f16x4*)(xgp + (size_t)g * 160 * 16);
      xgp += XG_TSTRIDE;
    }
    if (t > 0 && tid < 336) {
      f16x8 v = *(const f16x8*)(&hbuf[cur][tid * 8]);
      *(f16x8*)houtp = v;
      houtp += HO_TSTRIDE;
    }

#pragma unroll
    for (int kc = 0; kc < 5; ++kc) {
      f16x8 a = *(const f16x8*)(&hbuf[cur][lrow * HSTR + kc * 32 + lk8]);
#pragma unroll
      for (int g = 0; g < 4; ++g)
        acc[g] = __builtin_amdgcn_mfma_f32_16x16x32_f16(a, wh[g][kc], acc[g], 0, 0, 0);
    }

#pragma unroll
    for (int j = 0; j < 4; ++j) {
      float iv = sigf(acc[0][j]);
      float fv = sigf(acc[1][j]);
      float gv = tanh_f(acc[2][j]);
      float ov = sigf(acc[3][j]);
      float c = fv * creg[j] + iv * gv;
      creg[j] = c;
      float h = ov * tanh_f(c);
      hbuf[nxt][(r0 + j) * HSTR + col] = (f16)h;
    }

    BAR_LGKM();
  }
  if (tid < 336) {
    f16x8 v = *(const f16x8*)(&hbuf[0][tid * 8]);
    *(f16x8*)houtp = v;
  }
}

// ============================ rec1f2: layer-1 rec + xg2 (LDS) + layer-2 rec ============================
// 10 waves. Waves 0-7: layer-1 gates + h1 update; also xg2(t-1)=h1(t-1)@Wih2^T+b2
// into LDS dbuf (f32, stride-20 pad). Waves 8-9: layer-1 cols 128-159 (pad-heavy)
// + layer-2 recurrence 2 steps behind (h2(t-2) at step t), y stored to global.
// Loop t=0..65; one lgkm barrier/step.
__global__ __launch_bounds__(640, 2) void lstm_rec1f2(
    const f16* __restrict__ xg, const float* __restrict__ whh,
    const float* __restrict__ wih2, const float* __restrict__ bih2,
    const float* __restrict__ bhh2, const float* __restrict__ whh2,
    float* __restrict__ yout) {
  constexpr int H = 150, HSTR = 168, CPAD = 640;
  constexpr int XSTR2 = 20;   // xg2_lds col stride (f32): 2-way banks, 16B aligned
  constexpr int HSTR2 = 40;   // h2buf row stride (f16)
  constexpr size_t XG_TSTRIDE = (size_t)256 * CPAD * 16;
  __shared__ __align__(16) f16 hbuf[2][16 * HSTR];          // 21504 B
  __shared__ __align__(16) float xg2_lds[2][128 * XSTR2];   // 20480 B
  __shared__ __align__(16) f16 h2buf[2][16 * HSTR2];        // 2560 B
  const int tid = threadIdx.x;
  const int l = tid & 63, w = tid >> 6;
  const int lrow = l & 15, lk8 = (l >> 4) * 8, r0 = (l >> 4) * 4;
  const int col = w * 16 + lrow;
  const int bx = blockIdx.x, b0 = bx * 16;
  const bool xw = (w < 8);     // xg2 producers
  const bool l2w = (w >= 8);   // layer-2 waves
  const int c2 = w * 16 + lrow;          // xg2 col (w<8): 0..127
  const int cg2 = (w - 8) * 16 + lrow;   // h2 col (w>=8): 0..31

  for (int i = tid; i < 2 * 16 * HSTR / 8; i += 640) {
    f16x8 z = {};
    *(f16x8*)(&hbuf[0][0] + (size_t)i * 8) = z;
  }
  for (int i = tid; i < 2 * 16 * HSTR2 / 8; i += 640) {
    f16x8 z = {};
    *(f16x8*)(&h2buf[0][0] + (size_t)i * 8) = z;
  }

  // Whh1 frags (all waves)
  f16x8 wh[4][5];
#pragma unroll
  for (int g = 0; g < 4; ++g)
#pragma unroll
    for (int kc = 0; kc < 5; ++kc) {
      f16x8 v;
#pragma unroll
      for (int j = 0; j < 8; ++j) {
        int k = kc * 32 + lk8 + j;
        float x = (col < H && k < H) ? whh[((size_t)g * H + col) * H + k] : 0.f;
        v[j] = (f16)x;
      }
      wh[g][kc] = v;
    }
  // Wih2 frags + bias2 (waves 0-7)
  f16x8 wx2[5];
  float bias2 = 0.f;
  if (xw) {
#pragma unroll
    for (int kc = 0; kc < 5; ++kc) {
      f16x8 v;
#pragma unroll
      for (int j = 0; j < 8; ++j) {
        int k = kc * 32 + lk8 + j;
        float x = (k < 150) ? wih2[(size_t)c2 * 150 + k] : 0.f;
        v[j] = (f16)x;
      }
      wx2[kc] = v;
    }
    bias2 = bih2[c2] + bhh2[c2];
  }
  // Whh2 frags (waves 8-9): K=32 exact
  f16x8 wh2[4];
  if (l2w) {
#pragma unroll
    for (int g = 0; g < 4; ++g) {
      f16x8 v;
#pragma unroll
      for (int j = 0; j < 8; ++j)
        v[j] = (f16)whh2[(size_t)(g * 32 + cg2) * 32 + lk8 + j];
      wh2[g] = v;
    }
  }
  __syncthreads();

  float creg[4] = {0.f, 0.f, 0.f, 0.f};    // layer-1 c state
  float creg2[4] = {0.f, 0.f, 0.f, 0.f};   // layer-2 c state (waves 8-9)
  const f16* xgp = xg + ((size_t)bx * CPAD + col) * 16 + r0;
  f16x4 pv[4];
#pragma unroll
  for (int g = 0; g < 4; ++g) pv[g] = *(const f16x4*)(xgp + (size_t)g * 160 * 16);
  xgp += XG_TSTRIDE;

#pragma unroll 1
  for (int t = 0; t < T_STEPS + 2; ++t) {
    const int cur = t & 1, nxt = cur ^ 1;

    // ---- layer-1: consume xg(t), prefetch xg(t+1) ----
    f32x4 acc[4];
    if (t < T_STEPS) {
#pragma unroll
      for (int g = 0; g < 4; ++g) {
#pragma unroll
        for (int j = 0; j < 4; ++j) acc[g][j] = (float)pv[g][j];
      }
      if (t + 1 < T_STEPS) {
#pragma unroll
        for (int g = 0; g < 4; ++g) pv[g] = *(const f16x4*)(xgp + (size_t)g * 160 * 16);
        xgp += XG_TSTRIDE;
      }
    }

    // ---- MFMA: Whh1 gates(t) [t<64] + Wih2 xg2(t-1) [1<=t<=64] ----
    f32x4 accx = {bias2, bias2, bias2, bias2};
    if (t < T_STEPS) {
#pragma unroll
      for (int kc = 0; kc < 5; ++kc) {
        f16x8 a = *(const f16x8*)(&hbuf[cur][lrow * HSTR + kc * 32 + lk8]);
#pragma unroll
        for (int g = 0; g < 4; ++g)
          acc[g] = __builtin_amdgcn_mfma_f32_16x16x32_f16(a, wh[g][kc], acc[g], 0, 0, 0);
        if (xw)
          accx = __builtin_amdgcn_mfma_f32_16x16x32_f16(a, wx2[kc], accx, 0, 0, 0);
      }
    } else if (t == T_STEPS && xw) {
      // xg2(63) from h1(63) in hbuf[cur] (cur=0 at t=64)
#pragma unroll
      for (int kc = 0; kc < 5; ++kc) {
        f16x8 a = *(const f16x8*)(&hbuf[cur][lrow * HSTR + kc * 32 + lk8]);
        accx = __builtin_amdgcn_mfma_f32_16x16x32_f16(a, wx2[kc], accx, 0, 0, 0);
      }
    }
    if (xw && t >= 1 && t <= T_STEPS) {
      *(f32x4*)(&xg2_lds[cur][c2 * XSTR2 + r0]) = accx;
    }

    // ---- layer-2 (waves 8-9): s = t-2 ----
    if (l2w && t >= 2) {
      const int s = t - 2;
      f32x4 a2[4];
#pragma unroll
      for (int g = 0; g < 4; ++g)
        a2[g] = *(const f32x4*)(&xg2_lds[nxt][(g * 32 + cg2) * XSTR2 + r0]);
      f16x8 ah = *(const f16x8*)(&h2buf[nxt][lrow * HSTR2 + lk8]);
#pragma unroll
      for (int g = 0; g < 4; ++g)
        a2[g] = __builtin_amdgcn_mfma_f32_16x16x32_f16(ah, wh2[g], a2[g], 0, 0, 0);
#pragma unroll
      for (int j = 0; j < 4; ++j) {
        float iv = sigf(a2[0][j]);
        float fv = sigf(a2[1][j]);
        float gv = tanh_f(a2[2][j]);
        float ov = sigf(a2[3][j]);
        float c = fv * creg2[j] + iv * gv;
        creg2[j] = c;
        float h = ov * tanh_f(c);
        h2buf[cur][(r0 + j) * HSTR2 + cg2] = (f16)h;
        yout[((size_t)s * BATCH + b0 + r0 + j) * 32 + cg2] = h;
      }
    }

    // ---- layer-1 update (t<64) ----
    if (t < T_STEPS) {
#pragma unroll
      for (int j = 0; j < 4; ++j) {
        float iv = sigf(acc[0][j]);
        float fv = sigf(acc[1][j]);
        float gv = tanh_f(acc[2][j]);
        float ov = sigf(acc[3][j]);
        float c = fv * creg[j] + iv * gv;
        creg[j] = c;
        float h = ov * tanh_f(c);
        hbuf[nxt][(r0 + j) * HSTR + col] = (f16)h;
      }
    }

    BAR_LGKM();
  }
}

// ============================ fused fallback ============================
template <int IN_DIM, int H, int MODE>
__global__ __launch_bounds__(512, 2) void lstm_layer(
    const float* __restrict__ xin_f32, const f16* __restrict__ xin_f16,
    const float* __restrict__ w_ih, const float* __restrict__ w_hh,
    const float* __restrict__ b_ih, const float* __restrict__ b_hh,
    f16* __restrict__ hout, float* __restrict__ yout) {
  constexpr int KX = (IN_DIM + 31) / 32;
  constexpr int XSTR = KX * 32 + 8;
  constexpr int KH = (H + 31) / 32;
  constexpr int HSTR = KH * 32 + 8;
  constexpr int NPAD = ((H + 31) / 32) * 32;
  constexpr int NT = NPAD / 32;
  constexpr int GROUPS = NPAD * 4;
  constexpr int UPD_ITERS = (GROUPS + 511) / 512;
  constexpr int XIN_ELEMS = 16 * IN_DIM;
  constexpr int QX = (XIN_ELEMS + 511) / 512;
  constexpr int STG = (16 * XSTR) / 8;
  constexpr int HCP = (16 * HSTR) / 8;
  static_assert(MODE == 0 || XSTR == 168, "");

  __shared__ __align__(16) f16 xbuf[2][16 * XSTR];
  __shared__ __align__(16) f16 hbuf[16 * HSTR];
  __shared__ __align__(16) float gates[NPAD * 84];

  const int tid = threadIdx.x;
  const int l = tid & 63;
  const int wv = tid >> 6;
  const int gate = wv >> 1;
  const int half = wv & 1;
  const int lrow = l & 15;
  const int lk8 = (l >> 4) * 8;
  const int r0 = (l >> 4) * 4;
  const int b0 = blockIdx.x * 16;

  {
    f16* xf = &xbuf[0][0];
    for (int i = tid; i < 2 * 16 * XSTR; i += 512) xf[i] = (f16)0.f;
    for (int i = tid; i < 16 * HSTR; i += 512) hbuf[i] = (f16)0.f;
  }
  const int rbase = half * (NPAD / 2) + lrow;
  float bias_reg[NT];
#pragma unroll
  for (int nt = 0; nt < NT; ++nt) {
    int n = rbase + nt * 16;
    bias_reg[nt] = (n < H) ? (b_ih[gate * H + n] + b_hh[gate * H + n]) : 0.f;
  }
  f16x8 wx[KX][NT], wh[KH][NT];
#pragma unroll
  for (int kc = 0; kc < KX; ++kc)
#pragma unroll
    for (int nt = 0; nt < NT; ++nt) {
      f16x8 wq;
#pragma unroll
      for (int j = 0; j < 8; ++j) {
        int k = kc * 32 + lk8 + j;
        int r = rbase + nt * 16;
        float v = (r < H && k < IN_DIM) ? w_ih[(size_t)(gate * H + r) * IN_DIM + k] : 0.f;
        wq[j] = (f16)v;
      }
      wx[kc][nt] = wq;
    }
#pragma unroll
  for (int kc = 0; kc < KH; ++kc)
#pragma unroll
    for (int nt = 0; nt < NT; ++nt) {
      f16x8 wq;
#pragma unroll
      for (int j = 0; j < 8; ++j) {
        int k = kc * 32 + lk8 + j;
        int r = rbase + nt * 16;
        float v = (r < H && k < H) ? w_hh[(size_t)(gate * H + r) * H + k] : 0.f;
        wq[j] = (f16)v;
      }
      wh[kc][nt] = wq;
    }

  if constexpr (MODE == 0) {
#pragma unroll
    for (int q = 0; q < QX; ++q) {
      int idx = q * 512 + tid;
      if (idx < XIN_ELEMS) {
        float v = xin_f32[(size_t)b0 * IN_DIM + idx];
        int r = idx / IN_DIM, c = idx - r * IN_DIM;
        xbuf[0][r * XSTR + c] = (f16)v;
      }
    }
  } else {
    if (tid < STG) {
      f16x8 v = *(const f16x8*)(xin_f16 + (size_t)b0 * 168 + tid * 8);
      *(f16x8*)(&xbuf[0][tid * 8]) = v;
    }
  }
  __syncthreads();

  float creg[UPD_ITERS][4];
#pragma unroll
  for (int it = 0; it < UPD_ITERS; ++it)
#pragma unroll
    for (int j = 0; j < 4; ++j) creg[it][j] = 0.f;

  float xv[QX];
  f16x8 pv;

  for (int t = 0; t < T_STEPS; ++t) {
    const int cur = t & 1, nxt = cur ^ 1;
    if (t + 1 < T_STEPS) {
      if constexpr (MODE == 0) {
        const float* src = xin_f32 + ((size_t)(t + 1) * BATCH + b0) * IN_DIM;
#pragma unroll
        for (int q = 0; q < QX; ++q) {
          int idx = q * 512 + tid;
          xv[q] = (idx < XIN_ELEMS) ? src[idx] : 0.f;
        }
      } else {
        if (tid < STG)
          pv = *(const f16x8*)(xin_f16 + ((size_t)(t + 1) * BATCH + b0) * 168 + tid * 8);
      }
    }
    if constexpr (MODE != 2) {
      if (t > 0 && tid < HCP) {
        f16x8 v = *(const f16x8*)(&hbuf[tid * 8]);
        *(f16x8*)(hout + ((size_t)(t - 1) * BATCH + b0) * 168 + tid * 8) = v;
      }
    }
    f32x4 acc[NT];
#pragma unroll
    for (int nt = 0; nt < NT; ++nt) {
      float b = bias_reg[nt];
      acc[nt] = f32x4{b, b, b, b};
    }
    {
      const f16* xb = &xbuf[cur][0];
#pragma unroll
      for (int kc = 0; kc < KX; ++kc) {
        f16x8 a = *(const f16x8*)(xb + lrow * XSTR + kc * 32 + lk8);
#pragma unroll
        for (int nt = 0; nt < NT; ++nt)
          acc[nt] = __builtin_amdgcn_mfma_f32_16x16x32_f16(a, wx[kc][nt], acc[nt], 0, 0, 0);
      }
#pragma unroll
      for (int kc = 0; kc < KH; ++kc) {
        f16x8 a = *(const f16x8*)(hbuf + lrow * HSTR + kc * 32 + lk8);
#pragma unroll
        for (int nt = 0; nt < NT; ++nt)
          acc[nt] = __builtin_amdgcn_mfma_f32_16x16x32_f16(a, wh[kc][nt], acc[nt], 0, 0, 0);
      }
    }
#pragma unroll
    for (int nt = 0; nt < NT; ++nt) {
      int n = half * (NPAD / 2) + nt * 16 + lrow;
      *(f32x4*)(&gates[n * 84 + gate * 20 + r0]) = acc[nt];
    }
    BAR_LGKM();
    if (t + 1 < T_STEPS) {
      if constexpr (MODE == 0) {
#pragma unroll
        for (int q = 0; q < QX; ++q) {
          int idx = q * 512 + tid;
          if (idx < XIN_ELEMS) {
            int r = idx / IN_DIM, c = idx - r * IN_DIM;
            xbuf[nxt][r * XSTR + c] = (f16)xv[q];
          }
        }
      } else {
        if (tid < STG) *(f16x8*)(&xbuf[nxt][tid * 8]) = pv;
      }
    }
#pragma unroll
    for (int it = 0; it < UPD_ITERS; ++it) {
      int grp = it * 512 + tid;
      if (grp < GROUPS) {
        int n = grp % NPAD;
        int rb = (grp / NPAD) * 4;
        if (n < H) {
          f32x4 gi = *(const f32x4*)(&gates[n * 84 + 0 + rb]);
          f32x4 gf = *(const f32x4*)(&gates[n * 84 + 20 + rb]);
          f32x4 gg = *(const f32x4*)(&gates[n * 84 + 40 + rb]);
          f32x4 go = *(const f32x4*)(&gates[n * 84 + 60 + rb]);
#pragma unroll
          for (int j = 0; j < 4; ++j) {
            float iv = sigf(gi[j]);
            float fv = sigf(gf[j]);
            float gv = tanh_f(gg[j]);
            float ov = sigf(go[j]);
            float c = fv * creg[it][j] + iv * gv;
            creg[it][j] = c;
            float h = ov * tanh_f(c);
            hbuf[(rb + j) * HSTR + n] = (f16)h;
            if constexpr (MODE == 2) {
              yout[((size_t)t * BATCH + b0 + rb + j) * 32 + n] = h;
            }
          }
        }
      }
    }
    BAR_LGKM();
  }
  if constexpr (MODE != 2) {
    if (tid < HCP) {
      f16x8 v = *(const f16x8*)(&hbuf[tid * 8]);
      *(f16x8*)(hout + ((size_t)(T_STEPS - 1) * BATCH + b0) * 168 + tid * 8) = v;
    }
  }
}

extern "C" void kernel_launch(void* const* d_in, const int* in_sizes, int n_in,
                              void* d_out, int out_size, void* d_ws, size_t ws_size,
                              hipStream_t stream) {
  const float* x = (const float*)d_in[0];
  const float* wih0 = (const float*)d_in[1];
  const float* whh0 = (const float*)d_in[2];
  const float* bih0 = (const float*)d_in[3];
  const float* bhh0 = (const float*)d_in[4];
  const float* wih1 = (const float*)d_in[5];
  const float* whh1 = (const float*)d_in[6];
  const float* bih1 = (const float*)d_in[7];
  const float* bhh1 = (const float*)d_in[8];
  const float* wih2 = (const float*)d_in[9];
  const float* whh2 = (const float*)d_in[10];
  const float* bih2 = (const float*)d_in[11];
  const float* bhh2 = (const float*)d_in[12];

  const size_t HSEQ_BYTES = (size_t)T_STEPS * BATCH * 168 * sizeof(f16);   // 88,080,384
  const size_t XG_BYTES = (size_t)T_STEPS * BATCH * 640 * sizeof(f16);     // 335,544,320
  const size_t WPREP_BYTES = (size_t)640 * 168 * sizeof(f16);              // 215,040
  const size_t NEED = HSEQ_BYTES + XG_BYTES + 2 * WPREP_BYTES + 2 * 640 * sizeof(float);
  f16* hws = (f16*)d_ws;
  float* out = (float*)d_out;

  if (ws_size >= NEED) {
    char* base = (char*)d_ws;
    f16* xgbuf = (f16*)(base + HSEQ_BYTES);
    f16* wprep0 = (f16*)(base + HSEQ_BYTES + XG_BYTES);
    f16* wprep1 = (f16*)(base + HSEQ_BYTES + XG_BYTES + WPREP_BYTES);
    float* bias0 = (float*)(base + HSEQ_BYTES + XG_BYTES + 2 * WPREP_BYTES);
    float* bias1 = bias0 + 640;

    prep_w<<<dim3(846), dim3(256), 0, stream>>>(wih0, bih0, bhh0, wih1, bih1, bhh1,
                                                wprep0, wprep1, bias0, bias1);
    dim3 gg(2048), gb(512);
    dim3 rg(BATCH / 16), rb(640);
    gemm_xg4<145, 0><<<gg, gb, 0, stream>>>(x, nullptr, wprep0, bias0, xgbuf);
    lstm_rec<<<rg, rb, 0, stream>>>(xgbuf, whh0, hws);
    gemm_xg4<150, 1><<<gg, gb, 0, stream>>>(nullptr, hws, wprep1, bias1, xgbuf);
    lstm_rec1f2<<<rg, rb, 0, stream>>>(xgbuf, whh1, wih2, bih2, bhh2, whh2, out);
  } else {
    dim3 grid(BATCH / 16), block(512);
    lstm_layer<145, 150, 0><<<grid, block, 0, stream>>>(x, nullptr, wih0, whh0, bih0, bhh0, hws, nullptr);
    lstm_layer<150, 150, 1><<<grid, block, 0, stream>>>(nullptr, hws, wih1, whh1, bih1, bhh1, hws, nullptr);
    lstm_layer<150, 32, 2><<<grid, block, 0, stream>>>(nullptr, hws, wih2, whh2, bih2, bhh2, nullptr, out);
  }
}

// Round 12
// 604.166 us; speedup vs baseline: 1.0972x; 1.0972x over previous
//
#include <hip/hip_runtime.h>

// 3-layer LSTM (145->150->150->32), T=64, B=4096, fp16 MFMA, f32 state.
// Pipeline: prep_w -> gemm0(x->xg0) -> rec0(xg0->h0) -> gemm1(h0->xg1)
//        -> rec1f(xg1->xg2 fused w/ Wih2) -> rec32(xg2->out).
// R8: lgkm-only barriers (global stores never drained). R10: Wih2 GEMM fused in rec1.
// R11 FAILED (layer-2 chain inside rec1f's barrier loop hit max-wave) -> reverted.
// R12: rec32 4-row blocks grid 1024 (4 blocks/CU, was 2) to fix its 4-waves/CU
//      latency exposure; rec0 h-copy moved after MFMA issue (A-frag lgkm first).

typedef _Float16 f16;
typedef _Float16 f16x8 __attribute__((ext_vector_type(8)));
typedef _Float16 f16x4 __attribute__((ext_vector_type(4)));
typedef float f32x4 __attribute__((ext_vector_type(4)));

#define T_STEPS 64
#define BATCH 4096

__device__ __forceinline__ float fexp(float x) {
  return __builtin_amdgcn_exp2f(x * 1.44269504088896340736f);
}
__device__ __forceinline__ float sigf(float x) {
  return __builtin_amdgcn_rcpf(1.0f + fexp(-x));
}
__device__ __forceinline__ float tanh_f(float x) {
  return 1.0f - 2.0f * __builtin_amdgcn_rcpf(1.0f + fexp(2.0f * x));
}

#define BAR_LGKM() asm volatile("s_waitcnt lgkmcnt(0)\n\ts_barrier" ::: "memory")

// ============================ weight prep ============================
__global__ __launch_bounds__(256) void prep_w(
    const float* __restrict__ wih0, const float* __restrict__ bih0, const float* __restrict__ bhh0,
    const float* __restrict__ wih1, const float* __restrict__ bih1, const float* __restrict__ bhh1,
    f16* __restrict__ wprep0, f16* __restrict__ wprep1,
    float* __restrict__ bias0, float* __restrict__ bias1) {
  int idx = blockIdx.x * 256 + threadIdx.x;
  constexpr int WE = 640 * 168;
  if (idx < WE) {
    int c = idx / 168, k = idx - c * 168;
    int gate = c / 160, cg = c - gate * 160;
    float v = (cg < 150 && k < 145) ? wih0[(size_t)(gate * 150 + cg) * 145 + k] : 0.f;
    wprep0[idx] = (f16)v;
  } else if (idx < 2 * WE) {
    int e = idx - WE;
    int c = e / 168, k = e - c * 168;
    int gate = c / 160, cg = c - gate * 160;
    float v = (cg < 150 && k < 150) ? wih1[(size_t)(gate * 150 + cg) * 150 + k] : 0.f;
    wprep1[e] = (f16)v;
  } else if (idx < 2 * WE + 640) {
    int c = idx - 2 * WE;
    int gate = c / 160, cg = c - gate * 160;
    bias0[c] = (cg < 150) ? (bih0[gate * 150 + cg] + bhh0[gate * 150 + cg]) : 0.f;
  } else if (idx < 2 * WE + 1280) {
    int c = idx - 2 * WE - 640;
    int gate = c / 160, cg = c - gate * 160;
    bias1[c] = (cg < 150) ? (bih1[gate * 150 + cg] + bhh1[gate * 150 + cg]) : 0.f;
  }
}

// ============================ xg GEMM (R8, proven) ============================
template <int IN_DIM, int SRC_F16>
__global__ __launch_bounds__(512, 4) void gemm_xg4(
    const float* __restrict__ xin_f32, const f16* __restrict__ xin_f16,
    const f16* __restrict__ wprep, const float* __restrict__ bias_pre,
    f16* __restrict__ xg) {
  constexpr int ASTR = 168;
  __shared__ __align__(16) f16 A_lds[128 * ASTR];
  __shared__ __align__(16) f16 W_lds[64 * ASTR];
  __shared__ __align__(16) float bias_lds[640];
  const int tid = threadIdx.x;
  const int mtile = blockIdx.x;
  const int g0 = mtile * 128;

  if constexpr (SRC_F16) {
#pragma unroll
    for (int q = 0; q < 6; ++q) {
      int i = q * 512 + tid;
      if (i < 2688)
        *(f16x8*)(&A_lds[i * 8]) = *(const f16x8*)(xin_f16 + (size_t)g0 * ASTR + (size_t)i * 8);
    }
  } else {
#pragma unroll
    for (int q = 0; q < 10; ++q) {
      int idx = q * 512 + tid;
      int r = idx / 40, c4 = (idx - r * 40) * 4;
      f16x4 o;
      if (c4 + 4 <= IN_DIM) {
        f32x4 v;
        __builtin_memcpy(&v, xin_f32 + (size_t)(g0 + r) * IN_DIM + c4, 16);
#pragma unroll
        for (int j = 0; j < 4; ++j) o[j] = (f16)v[j];
      } else {
#pragma unroll
        for (int j = 0; j < 4; ++j)
          o[j] = (c4 + j < IN_DIM) ? (f16)xin_f32[(size_t)(g0 + r) * IN_DIM + c4 + j] : (f16)0.f;
      }
      *(f16x4*)(&A_lds[r * ASTR + c4]) = o;
    }
  }
  if (tid < 160) *(f32x4*)(&bias_lds[tid * 4]) = *(const f32x4*)(bias_pre + tid * 4);
#pragma unroll
  for (int q = 0; q < 3; ++q) {
    int i = q * 512 + tid;
    if (i < 1344) *(f16x8*)(&W_lds[i * 8]) = *(const f16x8*)(wprep + (size_t)i * 8);
  }
  BAR_LGKM();

  const int l = tid & 63, wv = tid >> 6;
  const int p = wv >> 1, cq = wv & 1;
  const int lrow = l & 15, lk8 = (l >> 4) * 8, r0 = (l >> 4) * 4;
  const int arow0 = (2 * p) * 16 + lrow;
  const int wrow0 = (2 * cq) * 16 + lrow;

  f16x8 pv0, pv1, pv2;
  for (int ch = 0; ch < 10; ++ch) {
    if (ch < 9) {
      const f16* wsrc = wprep + (size_t)(ch + 1) * 10752;
      pv0 = *(const f16x8*)(wsrc + (size_t)tid * 8);
      pv1 = *(const f16x8*)(wsrc + (size_t)(tid + 512) * 8);
      if (tid < 320) pv2 = *(const f16x8*)(wsrc + (size_t)(tid + 1024) * 8);
    }
    const int c0 = ch * 64 + (2 * cq) * 16 + lrow;
    const float bs0 = bias_lds[c0], bs1 = bias_lds[c0 + 16];
    f32x4 a00 = {bs0, bs0, bs0, bs0}, a01 = {bs1, bs1, bs1, bs1};
    f32x4 a10 = a00, a11 = a01;
#pragma unroll
    for (int kc = 0; kc < 5; ++kc) {
      f16x8 a0 = *(const f16x8*)(&A_lds[arow0 * ASTR + kc * 32 + lk8]);
      f16x8 a1 = *(const f16x8*)(&A_lds[(arow0 + 16) * ASTR + kc * 32 + lk8]);
      f16x8 b0 = *(const f16x8*)(&W_lds[wrow0 * ASTR + kc * 32 + lk8]);
      f16x8 b1 = *(const f16x8*)(&W_lds[(wrow0 + 16) * ASTR + kc * 32 + lk8]);
      a00 = __builtin_amdgcn_mfma_f32_16x16x32_f16(a0, b0, a00, 0, 0, 0);
      a01 = __builtin_amdgcn_mfma_f32_16x16x32_f16(a0, b1, a01, 0, 0, 0);
      a10 = __builtin_amdgcn_mfma_f32_16x16x32_f16(a1, b0, a10, 0, 0, 0);
      a11 = __builtin_amdgcn_mfma_f32_16x16x32_f16(a1, b1, a11, 0, 0, 0);
    }
    {
      f16x4 o;
      size_t rg0 = (size_t)(mtile * 8 + 2 * p);
#pragma unroll
      for (int j = 0; j < 4; ++j) o[j] = (f16)a00[j];
      *(f16x4*)(xg + (rg0 * 640 + c0) * 16 + r0) = o;
#pragma unroll
      for (int j = 0; j < 4; ++j) o[j] = (f16)a01[j];
      *(f16x4*)(xg + (rg0 * 640 + c0 + 16) * 16 + r0) = o;
#pragma unroll
      for (int j = 0; j < 4; ++j) o[j] = (f16)a10[j];
      *(f16x4*)(xg + ((rg0 + 1) * 640 + c0) * 16 + r0) = o;
#pragma unroll
      for (int j = 0; j < 4; ++j) o[j] = (f16)a11[j];
      *(f16x4*)(xg + ((rg0 + 1) * 640 + c0 + 16) * 16 + r0) = o;
    }
    if (ch < 9) {
      BAR_LGKM();
      *(f16x8*)(&W_lds[tid * 8]) = pv0;
      *(f16x8*)(&W_lds[(tid + 512) * 8]) = pv1;
      if (tid < 320) *(f16x8*)(&W_lds[(tid + 1024) * 8]) = pv2;
      BAR_LGKM();
    }
  }
}

// ============================ recurrent layer 0 ============================
// R12: h-copy issued AFTER the MFMA ds_reads (A-frag lgkm waits no longer queue
// behind the copy's LDS read).
__global__ __launch_bounds__(640, 2) void lstm_rec(
    const f16* __restrict__ xg, const float* __restrict__ whh,
    f16* __restrict__ hout) {
  constexpr int H = 150, HSTR = 168, CPAD = 640;
  __shared__ __align__(16) f16 hbuf[2][16 * HSTR];
  const int tid = threadIdx.x;
  const int l = tid & 63, w = tid >> 6;
  const int lrow = l & 15, lk8 = (l >> 4) * 8, r0 = (l >> 4) * 4;
  const int col = w * 16 + lrow;
  const int bx = blockIdx.x, b0 = bx * 16;

  for (int i = tid; i < 2 * 16 * HSTR / 8; i += 640) {
    f16x8 z = {};
    *(f16x8*)(&hbuf[0][0] + (size_t)i * 8) = z;
  }

  f16x8 wh[4][5];
#pragma unroll
  for (int g = 0; g < 4; ++g)
#pragma unroll
    for (int kc = 0; kc < 5; ++kc) {
      f16x8 v;
#pragma unroll
      for (int j = 0; j < 8; ++j) {
        int k = kc * 32 + lk8 + j;
        float x = (col < H && k < H) ? whh[((size_t)g * H + col) * H + k] : 0.f;
        v[j] = (f16)x;
      }
      wh[g][kc] = v;
    }
  __syncthreads();

  float creg[4] = {0.f, 0.f, 0.f, 0.f};
  f16x4 pv[4];
#pragma unroll
  for (int g = 0; g < 4; ++g)
    pv[g] = *(const f16x4*)(xg + ((size_t)bx * CPAD + g * 160 + col) * 16 + r0);

  for (int t = 0; t < T_STEPS; ++t) {
    const int cur = t & 1, nxt = cur ^ 1;

    // (1) consume xg(t)
    f32x4 acc[4];
#pragma unroll
    for (int g = 0; g < 4; ++g) {
#pragma unroll
      for (int j = 0; j < 4; ++j) acc[g][j] = (float)pv[g][j];
    }
    // (2) prefetch xg(t+1)
    if (t + 1 < T_STEPS) {
#pragma unroll
      for (int g = 0; g < 4; ++g)
        pv[g] = *(const f16x4*)(xg + ((size_t)((t + 1) * 256 + bx) * CPAD + g * 160 + col) * 16 + r0);
    }

    // (3) MFMA: A-frag ds_reads issue first
#pragma unroll
    for (int kc = 0; kc < 5; ++kc) {
      f16x8 a = *(const f16x8*)(&hbuf[cur][lrow * HSTR + kc * 32 + lk8]);
#pragma unroll
      for (int g = 0; g < 4; ++g)
        acc[g] = __builtin_amdgcn_mfma_f32_16x16x32_f16(a, wh[g][kc], acc[g], 0, 0, 0);
    }

    // (4) deferred coalesced h(t-1) store (after MFMA reads; never waited on)
    if (t > 0 && tid < 336) {
      f16x8 v = *(const f16x8*)(&hbuf[cur][tid * 8]);
      *(f16x8*)(hout + ((size_t)(t - 1) * BATCH + b0) * 168 + (size_t)tid * 8) = v;
    }

    // (5) in-register gate update
#pragma unroll
    for (int j = 0; j < 4; ++j) {
      float iv = sigf(acc[0][j]);
      float fv = sigf(acc[1][j]);
      float gv = tanh_f(acc[2][j]);
      float ov = sigf(acc[3][j]);
      float c = fv * creg[j] + iv * gv;
      creg[j] = c;
      float h = ov * tanh_f(c);
      hbuf[nxt][(r0 + j) * HSTR + col] = (f16)h;
    }

    BAR_LGKM();
  }
  if (tid < 336) {
    f16x8 v = *(const f16x8*)(&hbuf[0][tid * 8]);
    *(f16x8*)(hout + ((size_t)(T_STEPS - 1) * BATCH + b0) * 168 + (size_t)tid * 8) = v;
  }
}

// ============================ recurrent layer 1 + fused xg2 GEMM (R10, proven) ============================
__global__ __launch_bounds__(640, 2) void lstm_rec1f(
    const f16* __restrict__ xg, const float* __restrict__ whh,
    const float* __restrict__ wih2, const float* __restrict__ bih2,
    const float* __restrict__ bhh2, f16* __restrict__ xg2) {
  constexpr int H = 150, HSTR = 168, CPAD = 640;
  __shared__ __align__(16) f16 hbuf[2][16 * HSTR];
  const int tid = threadIdx.x;
  const int l = tid & 63, w = tid >> 6;
  const int lrow = l & 15, lk8 = (l >> 4) * 8, r0 = (l >> 4) * 4;
  const int col = w * 16 + lrow;
  const int bx = blockIdx.x;
  const bool xw = (w < 8);
  const int c2 = w * 16 + lrow;

  for (int i = tid; i < 2 * 16 * HSTR / 8; i += 640) {
    f16x8 z = {};
    *(f16x8*)(&hbuf[0][0] + (size_t)i * 8) = z;
  }

  f16x8 wh[4][5];
#pragma unroll
  for (int g = 0; g < 4; ++g)
#pragma unroll
    for (int kc = 0; kc < 5; ++kc) {
      f16x8 v;
#pragma unroll
      for (int j = 0; j < 8; ++j) {
        int k = kc * 32 + lk8 + j;
        float x = (col < H && k < H) ? whh[((size_t)g * H + col) * H + k] : 0.f;
        v[j] = (f16)x;
      }
      wh[g][kc] = v;
    }
  f16x8 wx2[5];
  float bias2 = 0.f;
  if (xw) {
#pragma unroll
    for (int kc = 0; kc < 5; ++kc) {
      f16x8 v;
#pragma unroll
      for (int j = 0; j < 8; ++j) {
        int k = kc * 32 + lk8 + j;
        float x = (k < 150) ? wih2[(size_t)c2 * 150 + k] : 0.f;
        v[j] = (f16)x;
      }
      wx2[kc] = v;
    }
    bias2 = bih2[c2] + bhh2[c2];
  }
  __syncthreads();

  float creg[4] = {0.f, 0.f, 0.f, 0.f};
  f16x4 pv[4];
#pragma unroll
  for (int g = 0; g < 4; ++g)
    pv[g] = *(const f16x4*)(xg + ((size_t)bx * CPAD + g * 160 + col) * 16 + r0);

  for (int t = 0; t < T_STEPS; ++t) {
    const int cur = t & 1, nxt = cur ^ 1;

    f32x4 acc[4];
#pragma unroll
    for (int g = 0; g < 4; ++g) {
#pragma unroll
      for (int j = 0; j < 4; ++j) acc[g][j] = (float)pv[g][j];
    }
    if (t + 1 < T_STEPS) {
#pragma unroll
      for (int g = 0; g < 4; ++g)
        pv[g] = *(const f16x4*)(xg + ((size_t)((t + 1) * 256 + bx) * CPAD + g * 160 + col) * 16 + r0);
    }

    f32x4 accx = {bias2, bias2, bias2, bias2};
#pragma unroll
    for (int kc = 0; kc < 5; ++kc) {
      f16x8 a = *(const f16x8*)(&hbuf[cur][lrow * HSTR + kc * 32 + lk8]);
#pragma unroll
      for (int g = 0; g < 4; ++g)
        acc[g] = __builtin_amdgcn_mfma_f32_16x16x32_f16(a, wh[g][kc], acc[g], 0, 0, 0);
      if (xw)
        accx = __builtin_amdgcn_mfma_f32_16x16x32_f16(a, wx2[kc], accx, 0, 0, 0);
    }
    if (xw && t > 0) {
      f16x4 o;
#pragma unroll
      for (int j = 0; j < 4; ++j) o[j] = (f16)accx[j];
      *(f16x4*)(xg2 + (((size_t)(t - 1) * 256 + bx) * 128 + c2) * 16 + r0) = o;
    }

#pragma unroll
    for (int j = 0; j < 4; ++j) {
      float iv = sigf(acc[0][j]);
      float fv = sigf(acc[1][j]);
      float gv = tanh_f(acc[2][j]);
      float ov = sigf(acc[3][j]);
      float c = fv * creg[j] + iv * gv;
      creg[j] = c;
      float h = ov * tanh_f(c);
      hbuf[nxt][(r0 + j) * HSTR + col] = (f16)h;
    }

    BAR_LGKM();
  }
  // epilogue: xg2(63) from h1(63) in hbuf[0]
  if (xw) {
    f32x4 accx = {bias2, bias2, bias2, bias2};
#pragma unroll
    for (int kc = 0; kc < 5; ++kc) {
      f16x8 a = *(const f16x8*)(&hbuf[0][lrow * HSTR + kc * 32 + lk8]);
      accx = __builtin_amdgcn_mfma_f32_16x16x32_f16(a, wx2[kc], accx, 0, 0, 0);
    }
    f16x4 o;
#pragma unroll
    for (int j = 0; j < 4; ++j) o[j] = (f16)accx[j];
    *(f16x4*)(xg2 + (((size_t)(T_STEPS - 1) * 256 + bx) * 128 + c2) * 16 + r0) = o;
  }
}

// ============================ layer 2 slim rec (H2=32), 4-row blocks ============================
// R12: grid 1024 (4 rows/block) = 4 blocks/CU, 8 waves/CU -- fixes the 4-waves/CU
// latency exposure of the grid-512 version. Active lanes l<16 (C rows 0..3).
__global__ __launch_bounds__(128) void lstm_rec32(
    const f16* __restrict__ xg2, const float* __restrict__ whh2,
    float* __restrict__ yout) {
  constexpr int HSTR2 = 40;
  __shared__ __align__(16) f16 hbuf2[2][16 * HSTR2];
  const int tid = threadIdx.x;
  const int l = tid & 63, w = tid >> 6;        // wave 0..1
  const int lrow = l & 15, lk8 = (l >> 4) * 8, r0 = (l >> 4) * 4;
  const int cg = w * 16 + lrow;                // h2 col 0..31
  const int p = blockIdx.x;                    // 0..1023
  const int rg = p >> 2;                       // xg2 16-row group
  const int quarter = p & 3;                   // 4-row slice
  const int b0 = p * 4;
  const bool active = (l < 16);                // C rows 0..3

  for (int i = tid; i < 2 * 16 * HSTR2 / 8; i += 128) {
    f16x8 z = {};
    *(f16x8*)(&hbuf2[0][0] + (size_t)i * 8) = z;
  }

  f16x8 wh2[4];
#pragma unroll
  for (int g = 0; g < 4; ++g) {
    f16x8 v;
#pragma unroll
    for (int j = 0; j < 8; ++j)
      v[j] = (f16)whh2[(size_t)(g * 32 + cg) * 32 + lk8 + j];
    wh2[g] = v;
  }
  __syncthreads();

  float creg[4] = {0.f, 0.f, 0.f, 0.f};
  f16x4 pv[4];
  if (active) {
#pragma unroll
    for (int g = 0; g < 4; ++g)
      pv[g] = *(const f16x4*)(xg2 + ((size_t)rg * 128 + g * 32 + cg) * 16 + quarter * 4);
  }

  for (int t = 0; t < T_STEPS; ++t) {
    const int cur = t & 1, nxt = cur ^ 1;

    f32x4 acc[4];
    if (active) {
#pragma unroll
      for (int g = 0; g < 4; ++g) {
#pragma unroll
        for (int j = 0; j < 4; ++j) acc[g][j] = (float)pv[g][j];
      }
      if (t + 1 < T_STEPS) {
#pragma unroll
        for (int g = 0; g < 4; ++g)
          pv[g] = *(const f16x4*)(xg2 + (((size_t)(t + 1) * 256 + rg) * 128 + g * 32 + cg) * 16 + quarter * 4);
      }
    } else {
#pragma unroll
      for (int g = 0; g < 4; ++g) acc[g] = f32x4{0.f, 0.f, 0.f, 0.f};
    }

    {
      f16x8 a = *(const f16x8*)(&hbuf2[cur][lrow * HSTR2 + lk8]);
#pragma unroll
      for (int g = 0; g < 4; ++g)
        acc[g] = __builtin_amdgcn_mfma_f32_16x16x32_f16(a, wh2[g], acc[g], 0, 0, 0);
    }

    if (active) {
#pragma unroll
      for (int j = 0; j < 4; ++j) {
        float iv = sigf(acc[0][j]);
        float fv = sigf(acc[1][j]);
        float gv = tanh_f(acc[2][j]);
        float ov = sigf(acc[3][j]);
        float c = fv * creg[j] + iv * gv;
        creg[j] = c;
        float h = ov * tanh_f(c);
        hbuf2[nxt][(r0 + j) * HSTR2 + cg] = (f16)h;
        yout[((size_t)t * BATCH + b0 + r0 + j) * 32 + cg] = h;
      }
    }

    BAR_LGKM();
  }
}

// ============================ fused fallback ============================
template <int IN_DIM, int H, int MODE>
__global__ __launch_bounds__(512, 2) void lstm_layer(
    const float* __restrict__ xin_f32, const f16* __restrict__ xin_f16,
    const float* __restrict__ w_ih, const float* __restrict__ w_hh,
    const float* __restrict__ b_ih, const float* __restrict__ b_hh,
    f16* __restrict__ hout, float* __restrict__ yout) {
  constexpr int KX = (IN_DIM + 31) / 32;
  constexpr int XSTR = KX * 32 + 8;
  constexpr int KH = (H + 31) / 32;
  constexpr int HSTR = KH * 32 + 8;
  constexpr int NPAD = ((H + 31) / 32) * 32;
  constexpr int NT = NPAD / 32;
  constexpr int GROUPS = NPAD * 4;
  constexpr int UPD_ITERS = (GROUPS + 511) / 512;
  constexpr int XIN_ELEMS = 16 * IN_DIM;
  constexpr int QX = (XIN_ELEMS + 511) / 512;
  constexpr int STG = (16 * XSTR) / 8;
  constexpr int HCP = (16 * HSTR) / 8;
  static_assert(MODE == 0 || XSTR == 168, "");

  __shared__ __align__(16) f16 xbuf[2][16 * XSTR];
  __shared__ __align__(16) f16 hbuf[16 * HSTR];
  __shared__ __align__(16) float gates[NPAD * 84];

  const int tid = threadIdx.x;
  const int l = tid & 63;
  const int wv = tid >> 6;
  const int gate = wv >> 1;
  const int half = wv & 1;
  const int lrow = l & 15;
  const int lk8 = (l >> 4) * 8;
  const int r0 = (l >> 4) * 4;
  const int b0 = blockIdx.x * 16;

  {
    f16* xf = &xbuf[0][0];
    for (int i = tid; i < 2 * 16 * XSTR; i += 512) xf[i] = (f16)0.f;
    for (int i = tid; i < 16 * HSTR; i += 512) hbuf[i] = (f16)0.f;
  }
  const int rbase = half * (NPAD / 2) + lrow;
  float bias_reg[NT];
#pragma unroll
  for (int nt = 0; nt < NT; ++nt) {
    int n = rbase + nt * 16;
    bias_reg[nt] = (n < H) ? (b_ih[gate * H + n] + b_hh[gate * H + n]) : 0.f;
  }
  f16x8 wx[KX][NT], wh[KH][NT];
#pragma unroll
  for (int kc = 0; kc < KX; ++kc)
#pragma unroll
    for (int nt = 0; nt < NT; ++nt) {
      f16x8 wq;
#pragma unroll
      for (int j = 0; j < 8; ++j) {
        int k = kc * 32 + lk8 + j;
        int r = rbase + nt * 16;
        float v = (r < H && k < IN_DIM) ? w_ih[(size_t)(gate * H + r) * IN_DIM + k] : 0.f;
        wq[j] = (f16)v;
      }
      wx[kc][nt] = wq;
    }
#pragma unroll
  for (int kc = 0; kc < KH; ++kc)
#pragma unroll
    for (int nt = 0; nt < NT; ++nt) {
      f16x8 wq;
#pragma unroll
      for (int j = 0; j < 8; ++j) {
        int k = kc * 32 + lk8 + j;
        int r = rbase + nt * 16;
        float v = (r < H && k < H) ? w_hh[(size_t)(gate * H + r) * H + k] : 0.f;
        wq[j] = (f16)v;
      }
      wh[kc][nt] = wq;
    }

  if constexpr (MODE == 0) {
#pragma unroll
    for (int q = 0; q < QX; ++q) {
      int idx = q * 512 + tid;
      if (idx < XIN_ELEMS) {
        float v = xin_f32[(size_t)b0 * IN_DIM + idx];
        int r = idx / IN_DIM, c = idx - r * IN_DIM;
        xbuf[0][r * XSTR + c] = (f16)v;
      }
    }
  } else {
    if (tid < STG) {
      f16x8 v = *(const f16x8*)(xin_f16 + (size_t)b0 * 168 + tid * 8);
      *(f16x8*)(&xbuf[0][tid * 8]) = v;
    }
  }
  __syncthreads();

  float creg[UPD_ITERS][4];
#pragma unroll
  for (int it = 0; it < UPD_ITERS; ++it)
#pragma unroll
    for (int j = 0; j < 4; ++j) creg[it][j] = 0.f;

  float xv[QX];
  f16x8 pv;

  for (int t = 0; t < T_STEPS; ++t) {
    const int cur = t & 1, nxt = cur ^ 1;
    if (t + 1 < T_STEPS) {
      if constexpr (MODE == 0) {
        const float* src = xin_f32 + ((size_t)(t + 1) * BATCH + b0) * IN_DIM;
#pragma unroll
        for (int q = 0; q < QX; ++q) {
          int idx = q * 512 + tid;
          xv[q] = (idx < XIN_ELEMS) ? src[idx] : 0.f;
        }
      } else {
        if (tid < STG)
          pv = *(const f16x8*)(xin_f16 + ((size_t)(t + 1) * BATCH + b0) * 168 + tid * 8);
      }
    }
    if constexpr (MODE != 2) {
      if (t > 0 && tid < HCP) {
        f16x8 v = *(const f16x8*)(&hbuf[tid * 8]);
        *(f16x8*)(hout + ((size_t)(t - 1) * BATCH + b0) * 168 + tid * 8) = v;
      }
    }
    f32x4 acc[NT];
#pragma unroll
    for (int nt = 0; nt < NT; ++nt) {
      float b = bias_reg[nt];
      acc[nt] = f32x4{b, b, b, b};
    }
    {
      const f16* xb = &xbuf[cur][0];
#pragma unroll
      for (int kc = 0; kc < KX; ++kc) {
        f16x8 a = *(const f16x8*)(xb + lrow * XSTR + kc * 32 + lk8);
#pragma unroll
        for (int nt = 0; nt < NT; ++nt)
          acc[nt] = __builtin_amdgcn_mfma_f32_16x16x32_f16(a, wx[kc][nt], acc[nt], 0, 0, 0);
      }
#pragma unroll
      for (int kc = 0; kc < KH; ++kc) {
        f16x8 a = *(const f16x8*)(hbuf + lrow * HSTR + kc * 32 + lk8);
#pragma unroll
        for (int nt = 0; nt < NT; ++nt)
          acc[nt] = __builtin_amdgcn_mfma_f32_16x16x32_f16(a, wh[kc][nt], acc[nt], 0, 0, 0);
      }
    }
#pragma unroll
    for (int nt = 0; nt < NT; ++nt) {
      int n = half * (NPAD / 2) + nt * 16 + lrow;
      *(f32x4*)(&gates[n * 84 + gate * 20 + r0]) = acc[nt];
    }
    BAR_LGKM();
    if (t + 1 < T_STEPS) {
      if constexpr (MODE == 0) {
#pragma unroll
        for (int q = 0; q < QX; ++q) {
          int idx = q * 512 + tid;
          if (idx < XIN_ELEMS) {
            int r = idx / IN_DIM, c = idx - r * IN_DIM;
            xbuf[nxt][r * XSTR + c] = (f16)xv[q];
          }
        }
      } else {
        if (tid < STG) *(f16x8*)(&xbuf[nxt][tid * 8]) = pv;
      }
    }
#pragma unroll
    for (int it = 0; it < UPD_ITERS; ++it) {
      int grp = it * 512 + tid;
      if (grp < GROUPS) {
        int n = grp % NPAD;
        int rb = (grp / NPAD) * 4;
        if (n < H) {
          f32x4 gi = *(const f32x4*)(&gates[n * 84 + 0 + rb]);
          f32x4 gf = *(const f32x4*)(&gates[n * 84 + 20 + rb]);
          f32x4 gg = *(const f32x4*)(&gates[n * 84 + 40 + rb]);
          f32x4 go = *(const f32x4*)(&gates[n * 84 + 60 + rb]);
#pragma unroll
          for (int j = 0; j < 4; ++j) {
            float iv = sigf(gi[j]);
            float fv = sigf(gf[j]);
            float gv = tanh_f(gg[j]);
            float ov = sigf(go[j]);
            float c = fv * creg[it][j] + iv * gv;
            creg[it][j] = c;
            float h = ov * tanh_f(c);
            hbuf[(rb + j) * HSTR + n] = (f16)h;
            if constexpr (MODE == 2) {
              yout[((size_t)t * BATCH + b0 + rb + j) * 32 + n] = h;
            }
          }
        }
      }
    }
    BAR_LGKM();
  }
  if constexpr (MODE != 2) {
    if (tid < HCP) {
      f16x8 v = *(const f16x8*)(&hbuf[tid * 8]);
      *(f16x8*)(hout + ((size_t)(T_STEPS - 1) * BATCH + b0) * 168 + tid * 8) = v;
    }
  }
}

extern "C" void kernel_launch(void* const* d_in, const int* in_sizes, int n_in,
                              void* d_out, int out_size, void* d_ws, size_t ws_size,
                              hipStream_t stream) {
  const float* x = (const float*)d_in[0];
  const float* wih0 = (const float*)d_in[1];
  const float* whh0 = (const float*)d_in[2];
  const float* bih0 = (const float*)d_in[3];
  const float* bhh0 = (const float*)d_in[4];
  const float* wih1 = (const float*)d_in[5];
  const float* whh1 = (const float*)d_in[6];
  const float* bih1 = (const float*)d_in[7];
  const float* bhh1 = (const float*)d_in[8];
  const float* wih2 = (const float*)d_in[9];
  const float* whh2 = (const float*)d_in[10];
  const float* bih2 = (const float*)d_in[11];
  const float* bhh2 = (const float*)d_in[12];

  const size_t HSEQ_BYTES = (size_t)T_STEPS * BATCH * 168 * sizeof(f16);   // 88,080,384
  const size_t XG_BYTES = (size_t)T_STEPS * BATCH * 640 * sizeof(f16);     // 335,544,320
  const size_t WPREP_BYTES = (size_t)640 * 168 * sizeof(f16);              // 215,040
  const size_t NEED = HSEQ_BYTES + XG_BYTES + 2 * WPREP_BYTES + 2 * 640 * sizeof(float);
  f16* hws = (f16*)d_ws;
  float* out = (float*)d_out;

  if (ws_size >= NEED) {
    char* base = (char*)d_ws;
    f16* xgbuf = (f16*)(base + HSEQ_BYTES);
    f16* wprep0 = (f16*)(base + HSEQ_BYTES + XG_BYTES);
    f16* wprep1 = (f16*)(base + HSEQ_BYTES + XG_BYTES + WPREP_BYTES);
    float* bias0 = (float*)(base + HSEQ_BYTES + XG_BYTES + 2 * WPREP_BYTES);
    float* bias1 = bias0 + 640;
    f16* xg2buf = hws;  // aliases h-seq buffer: dead after gemm1 reads it

    prep_w<<<dim3(846), dim3(256), 0, stream>>>(wih0, bih0, bhh0, wih1, bih1, bhh1,
                                                wprep0, wprep1, bias0, bias1);
    dim3 gg(2048), gb(512);
    dim3 rg(BATCH / 16), rb(640);
    gemm_xg4<145, 0><<<gg, gb, 0, stream>>>(x, nullptr, wprep0, bias0, xgbuf);
    lstm_rec<<<rg, rb, 0, stream>>>(xgbuf, whh0, hws);
    gemm_xg4<150, 1><<<gg, gb, 0, stream>>>(nullptr, hws, wprep1, bias1, xgbuf);
    lstm_rec1f<<<rg, rb, 0, stream>>>(xgbuf, whh1, wih2, bih2, bhh2, xg2buf);
    lstm_rec32<<<dim3(1024), dim3(128), 0, stream>>>(xg2buf, whh2, out);
  } else {
    dim3 grid(BATCH / 16), block(512);
    lstm_layer<145, 150, 0><<<grid, block, 0, stream>>>(x, nullptr, wih0, whh0, bih0, bhh0, hws, nullptr);
    lstm_layer<150, 150, 1><<<grid, block, 0, stream>>>(nullptr, hws, wih1, whh1, bih1, bhh1, hws, nullptr);
    lstm_layer<150, 32, 2><<<grid, block, 0, stream>>>(nullptr, hws, wih2, whh2, bih2, bhh2, nullptr, out);
  }
}